// Round 1
// baseline (83876.526 us; speedup 1.0000x reference)
//
#include <hip/hip_runtime.h>
#include <stdint.h>

// DSNN: 3-layer spiking net, B=16384, IN=128 (x-split -> 256), H=512, 127 steps.
// One WG owns 8 batch rows; all per-row state lives in registers for the whole
// simulation. Spikes are binary -> layer GEMMs become wave-uniform conditional
// row-accumulations of W (branch on SGPR mask, no divergence).

#define ALPHA 0.9f
#define BETA 0.85f
#define NSTEPS 127          // SIM_TIME - 1
#define HDIM 512
#define INDIM 128
#define XDIM 256
#define RPW 8               // rows per workgroup
#define THREADS 256         // each thread owns cols {2t, 2t+1}

__global__ __launch_bounds__(THREADS, 2)
void dsnn_kernel(const float* __restrict__ inputs,
                 const float* __restrict__ W0,
                 const float* __restrict__ W1,
                 const float* __restrict__ W2,
                 float* __restrict__ out)
{
    __shared__ float xc[RPW][XDIM];                 // 8 KB input staging
    __shared__ uint32_t rm0_u32[HDIM / 4];          // 512 B: per-col 8-row spike mask, layer 0
    __shared__ uint32_t rm1_u32[HDIM / 4];          // 512 B: layer 1

    const int t = threadIdx.x;
    const int r0 = blockIdx.x * RPW;

    // ---- stage x = concat(relu(in), relu(-in)) into LDS ----
    for (int idx = t; idx < RPW * INDIM; idx += THREADS) {
        const int r = idx >> 7;          // /128
        const int i = idx & 127;
        const float v = inputs[(size_t)(r0 + r) * INDIM + i];
        xc[r][i]          = fmaxf(v, 0.0f);
        xc[r][i + INDIM]  = fmaxf(-v, 0.0f);
    }
    __syncthreads();

    // ---- h0 = x @ W0 (time-invariant), cols 2t,2t+1 for 8 rows ----
    float2 h0[RPW];
#pragma unroll
    for (int r = 0; r < RPW; ++r) h0[r] = make_float2(0.0f, 0.0f);

    {
        const float2* W0v = (const float2*)W0;      // row i at W0v[i*256 + t]
        for (int i = 0; i < XDIM; ++i) {
            const float2 w = W0v[i * (HDIM / 2) + t];
#pragma unroll
            for (int r = 0; r < RPW; ++r) {
                const float xv = xc[r][i];
                h0[r].x += xv * w.x;
                h0[r].y += xv * w.y;
            }
        }
    }

    // ---- per-row, per-col state in registers ----
    float2 m0[RPW], s1[RPW], m1[RPW], s2[RPW], m2[RPW];
#pragma unroll
    for (int r = 0; r < RPW; ++r) {
        m0[r] = make_float2(0.0f, 0.0f);
        s1[r] = make_float2(0.0f, 0.0f);
        m1[r] = make_float2(0.0f, 0.0f);
        s2[r] = make_float2(0.0f, 0.0f);
        m2[r] = make_float2(0.0f, 0.0f);
    }

    const float2* W1v = (const float2*)W1;
    const float2* W2v = (const float2*)W2;
    uint16_t* rm0_u16 = (uint16_t*)rm0_u32;
    uint16_t* rm1_u16 = (uint16_t*)rm1_u32;

    for (int step = 0; step < NSTEPS; ++step) {
        // ===== layer 0: m0 = beta*m0 + h0; spike if m0-1>0; reset =====
        {
            uint32_t b0 = 0, b1 = 0;
#pragma unroll
            for (int r = 0; r < RPW; ++r) {
                m0[r].x = BETA * m0[r].x + h0[r].x;
                m0[r].y = BETA * m0[r].y + h0[r].y;
                if (m0[r].x - 1.0f > 0.0f) { b0 |= (1u << r); m0[r].x = 0.0f; }
                if (m0[r].y - 1.0f > 0.0f) { b1 |= (1u << r); m0[r].y = 0.0f; }
            }
            rm0_u16[t] = (uint16_t)(b0 | (b1 << 8));
        }
        __syncthreads();

        // ===== layer 1: h1 = spk0 @ W1 (sparse row-accumulate) =====
        {
            float2 acc[RPW];
#pragma unroll
            for (int r = 0; r < RPW; ++r) acc[r] = make_float2(0.0f, 0.0f);

            for (int j4 = 0; j4 < HDIM / 4; ++j4) {
                const uint32_t m4 =
                    (uint32_t)__builtin_amdgcn_readfirstlane((int)rm0_u32[j4]);
                if (m4 == 0) continue;
#pragma unroll
                for (int k = 0; k < 4; ++k) {
                    const uint32_t mb = (m4 >> (8 * k)) & 0xffu;
                    if (mb == 0) continue;
                    const int j = j4 * 4 + k;
                    const float2 w = W1v[j * (HDIM / 2) + t];
#pragma unroll
                    for (int r = 0; r < RPW; ++r) {
                        if (mb & (1u << r)) { acc[r].x += w.x; acc[r].y += w.y; }
                    }
                }
            }

            uint32_t b0 = 0, b1 = 0;
#pragma unroll
            for (int r = 0; r < RPW; ++r) {
                s1[r].x = ALPHA * s1[r].x + acc[r].x;
                s1[r].y = ALPHA * s1[r].y + acc[r].y;
                m1[r].x = BETA * m1[r].x + s1[r].x;
                m1[r].y = BETA * m1[r].y + s1[r].y;
                if (m1[r].x - 1.0f > 0.0f) { b0 |= (1u << r); m1[r].x = 0.0f; }
                if (m1[r].y - 1.0f > 0.0f) { b1 |= (1u << r); m1[r].y = 0.0f; }
            }
            rm1_u16[t] = (uint16_t)(b0 | (b1 << 8));
        }
        __syncthreads();

        // ===== layer 2: h2 = spk1 @ W2; s2,m2 update; no reset =====
        {
            float2 acc[RPW];
#pragma unroll
            for (int r = 0; r < RPW; ++r) acc[r] = make_float2(0.0f, 0.0f);

            for (int j4 = 0; j4 < HDIM / 4; ++j4) {
                const uint32_t m4 =
                    (uint32_t)__builtin_amdgcn_readfirstlane((int)rm1_u32[j4]);
                if (m4 == 0) continue;
#pragma unroll
                for (int k = 0; k < 4; ++k) {
                    const uint32_t mb = (m4 >> (8 * k)) & 0xffu;
                    if (mb == 0) continue;
                    const int j = j4 * 4 + k;
                    const float2 w = W2v[j * (HDIM / 2) + t];
#pragma unroll
                    for (int r = 0; r < RPW; ++r) {
                        if (mb & (1u << r)) { acc[r].x += w.x; acc[r].y += w.y; }
                    }
                }
            }

#pragma unroll
            for (int r = 0; r < RPW; ++r) {
                s2[r].x = ALPHA * s2[r].x + acc[r].x;
                s2[r].y = ALPHA * s2[r].y + acc[r].y;
                m2[r].x = BETA * m2[r].x + s2[r].x;
                m2[r].y = BETA * m2[r].y + s2[r].y;
            }
        }
        __syncthreads();   // protect rm0 rewrite next step vs layer-2 readers done
    }

    // ---- write final layer-2 membrane ----
    float2* outv = (float2*)out;
#pragma unroll
    for (int r = 0; r < RPW; ++r) {
        outv[(size_t)(r0 + r) * (HDIM / 2) + t] = m2[r];
    }
}

extern "C" void kernel_launch(void* const* d_in, const int* in_sizes, int n_in,
                              void* d_out, int out_size, void* d_ws, size_t ws_size,
                              hipStream_t stream) {
    const float* inputs = (const float*)d_in[0];   // 16384 x 128
    const float* W0     = (const float*)d_in[1];   // 256 x 512
    const float* W1     = (const float*)d_in[2];   // 512 x 512
    const float* W2     = (const float*)d_in[3];   // 512 x 512
    float* out          = (float*)d_out;           // 16384 x 512

    const int B = 16384;
    dim3 grid(B / RPW);      // 2048 workgroups, 8 rows each
    dim3 block(THREADS);
    dsnn_kernel<<<grid, block, 0, stream>>>(inputs, W0, W1, W2, out);
}

// Round 4
// 33386.298 us; speedup vs baseline: 2.5123x; 2.5123x over previous
//
#include <hip/hip_runtime.h>
#include <stdint.h>

// DSNN bit-exact fp32. Facts driving the design:
//  - R1 (fp32, sequential-j, conditional adds) matched np ref with absmax 0.0
//    -> arithmetic form is bit-reproducible. R2 (bf16 hi/lo MFMA, ~1e-4 h
//    error) failed at 511: spike decisions amplify any numeric delta. So:
//    fp32, j-ascending, single-accumulator fma only. No MFMA.
//  - Dense fmaf with spike in {0.0,1.0} is bitwise == conditional add
//    (fma(1,w,a)=round(a+w), fma(0,w,a)=a; +0.0 preserved) and removes all
//    mask/branch overhead -> ~1 VALU inst per MAC.
//  - 32 rows/WG amortizes W streaming (L2-resident, 130 GB total).
//  - v_pk_fma_f32 dropped: CDNA4 fp32 peak (157.3 TF) is the SCALAR SIMD-32
//    rate; pk is 2-pass, no FLOP gain, and the asm constraint broke R3.

typedef __attribute__((ext_vector_type(4))) float f32x4;

#define ALPHA 0.9f
#define BETA 0.85f
#define NSTEPS 127
#define WGT 1024
#define ROWS 32
#define CPAD 36     // spkbuf col stride (floats); 16B-aligned, breaks worst banking
#define HPAD 516    // h0buf row stride (floats)

// Update forms copied verbatim from R1 (bit-exact-verified vs np reference).
#define LIF_L0(M, H, SP) { float _m = BETA * (M) + (H); \
    const bool _b = (_m - 1.0f) > 0.0f; (M) = _b ? 0.0f : _m; \
    (SP) = _b ? 1.0f : 0.0f; }
#define LIF_MID(S, M, A, SP) { (S) = ALPHA * (S) + (A); \
    float _m = BETA * (M) + (S); const bool _b = (_m - 1.0f) > 0.0f; \
    (M) = _b ? 0.0f : _m; (SP) = _b ? 1.0f : 0.0f; }
#define LIF_OUT(S, M, A) { (S) = ALPHA * (S) + (A); (M) = BETA * (M) + (S); }

__global__ __launch_bounds__(WGT, 4)
void dsnn_kernel(const float* __restrict__ x,
                 const float* __restrict__ W0,
                 const float* __restrict__ W1,
                 const float* __restrict__ W2,
                 float* __restrict__ out)
{
    __shared__ float spkbuf[512 * CPAD];   // 73728 B, [col][row] (x-stage, then spikes)
    __shared__ float h0buf[ROWS * HPAD];   // 66048 B, [row][col]

    const int t  = threadIdx.x;
    const int c4 = (t & 127) * 4;          // this thread's cols c4..c4+3
    const int g4 = (t >> 7) * 4;           // this thread's rows g4..g4+3 (wave-uniform)
    const int r0 = blockIdx.x * ROWS;

    // ---- stage x (pos/neg split) into spkbuf [i][row], i = 0..255 ----
    for (int k = t; k < 256 * ROWS; k += WGT) {
        const int i = k >> 5;
        const int r = k & 31;
        const float v = (i < 128) ? x[(size_t)(r0 + r) * 128 + i]
                                  : -x[(size_t)(r0 + r) * 128 + (i - 128)];
        spkbuf[i * CPAD + r] = fmaxf(v, 0.0f);
    }
    __syncthreads();

    float acc[4][4];   // [row r][col cc]

    // acc[r][cc] += buf[j][g4+r] * W[j][c4+cc], j ascending (bit-exact order)
    auto gemm = [&](const float* Wcol, int K) {
        #pragma unroll 4
        for (int j = 0; j < K; ++j) {
            const f32x4 s4 = *(const f32x4*)(spkbuf + j * CPAD + g4);   // wave-uniform bcast
            const f32x4 wv = *(const f32x4*)(Wcol + (size_t)j * 512);
            #pragma unroll
            for (int r = 0; r < 4; ++r) {
                acc[r][0] = fmaf(s4[r], wv.x, acc[r][0]);
                acc[r][1] = fmaf(s4[r], wv.y, acc[r][1]);
                acc[r][2] = fmaf(s4[r], wv.z, acc[r][2]);
                acc[r][3] = fmaf(s4[r], wv.w, acc[r][3]);
            }
        }
    };

    // ---- h0 = x @ W0 (time-invariant), park in LDS to free VGPRs ----
    #pragma unroll
    for (int r = 0; r < 4; ++r)
        #pragma unroll
        for (int cc = 0; cc < 4; ++cc) acc[r][cc] = 0.0f;
    gemm(W0 + c4, 256);
    #pragma unroll
    for (int r = 0; r < 4; ++r) {
        f32x4 hv = { acc[r][0], acc[r][1], acc[r][2], acc[r][3] };
        *(f32x4*)(h0buf + (g4 + r) * HPAD + c4) = hv;
    }
    __syncthreads();   // all x-reads done before spkbuf is reused for spikes

    // ---- recurrent state in registers ----
    float m0[4][4], s1[4][4], m1[4][4], s2[4][4], m2[4][4];
    #pragma unroll
    for (int r = 0; r < 4; ++r)
        #pragma unroll
        for (int cc = 0; cc < 4; ++cc) {
            m0[r][cc] = 0.f; s1[r][cc] = 0.f; m1[r][cc] = 0.f;
            s2[r][cc] = 0.f; m2[r][cc] = 0.f;
        }

    float sarr[4][4];   // [cc][r] spike staging for transposed LDS write

    for (int step = 0; step < NSTEPS; ++step) {
        // ===== layer 0: m0 = BETA*m0 + h0; spike; reset; spikes -> spkbuf =====
        #pragma unroll
        for (int r = 0; r < 4; ++r) {
            const f32x4 hv = *(const f32x4*)(h0buf + (g4 + r) * HPAD + c4);
            LIF_L0(m0[r][0], hv.x, sarr[0][r]);
            LIF_L0(m0[r][1], hv.y, sarr[1][r]);
            LIF_L0(m0[r][2], hv.z, sarr[2][r]);
            LIF_L0(m0[r][3], hv.w, sarr[3][r]);
        }
        #pragma unroll
        for (int cc = 0; cc < 4; ++cc) {
            f32x4 sv = { sarr[cc][0], sarr[cc][1], sarr[cc][2], sarr[cc][3] };
            *(f32x4*)(spkbuf + (c4 + cc) * CPAD + g4) = sv;
        }
        __syncthreads();                       // A: L0 spikes visible

        // ===== layer 1: h1 = spk0 @ W1 =====
        #pragma unroll
        for (int r = 0; r < 4; ++r)
            #pragma unroll
            for (int cc = 0; cc < 4; ++cc) acc[r][cc] = 0.0f;
        gemm(W1 + c4, 512);
        __syncthreads();                       // B: all reads of L0 spikes done

        #pragma unroll
        for (int r = 0; r < 4; ++r) {
            LIF_MID(s1[r][0], m1[r][0], acc[r][0], sarr[0][r]);
            LIF_MID(s1[r][1], m1[r][1], acc[r][1], sarr[1][r]);
            LIF_MID(s1[r][2], m1[r][2], acc[r][2], sarr[2][r]);
            LIF_MID(s1[r][3], m1[r][3], acc[r][3], sarr[3][r]);
        }
        #pragma unroll
        for (int cc = 0; cc < 4; ++cc) {
            f32x4 sv = { sarr[cc][0], sarr[cc][1], sarr[cc][2], sarr[cc][3] };
            *(f32x4*)(spkbuf + (c4 + cc) * CPAD + g4) = sv;
        }
        __syncthreads();                       // C: L1 spikes visible

        // ===== layer 2: h2 = spk1 @ W2; s2,m2 update; no reset =====
        #pragma unroll
        for (int r = 0; r < 4; ++r)
            #pragma unroll
            for (int cc = 0; cc < 4; ++cc) acc[r][cc] = 0.0f;
        gemm(W2 + c4, 512);
        #pragma unroll
        for (int r = 0; r < 4; ++r) {
            LIF_OUT(s2[r][0], m2[r][0], acc[r][0]);
            LIF_OUT(s2[r][1], m2[r][1], acc[r][1]);
            LIF_OUT(s2[r][2], m2[r][2], acc[r][2]);
            LIF_OUT(s2[r][3], m2[r][3], acc[r][3]);
        }
        __syncthreads();                       // D: L1-spike reads done before next L0 write
    }

    // ---- write final m2 ----
    #pragma unroll
    for (int r = 0; r < 4; ++r) {
        f32x4 ov = { m2[r][0], m2[r][1], m2[r][2], m2[r][3] };
        *(f32x4*)(out + (size_t)(r0 + g4 + r) * 512 + c4) = ov;
    }
}

extern "C" void kernel_launch(void* const* d_in, const int* in_sizes, int n_in,
                              void* d_out, int out_size, void* d_ws, size_t ws_size,
                              hipStream_t stream) {
    const float* inputs = (const float*)d_in[0];   // 16384 x 128
    const float* W0     = (const float*)d_in[1];   // 256 x 512
    const float* W1     = (const float*)d_in[2];   // 512 x 512
    const float* W2     = (const float*)d_in[3];   // 512 x 512
    float* out          = (float*)d_out;           // 16384 x 512

    dim3 grid(16384 / ROWS);     // 512 workgroups, 32 rows each
    dim3 block(WGT);
    dsnn_kernel<<<grid, block, 0, stream>>>(inputs, W0, W1, W2, out);
}